// Round 1
// baseline (758.220 us; speedup 1.0000x reference)
//
#include <hip/hip_runtime.h>
#include <hip/hip_bf16.h>
#include <stdint.h>

// Problem constants (from reference)
#define N_NODES  4096
#define EMB_DIM  512
#define N_HEADS  8
#define K_SPARSE 128
#define HEAD_DIM 64   // EMB_DIM / N_HEADS

typedef __attribute__((ext_vector_type(8))) __bf16 bf16x8;
typedef __attribute__((ext_vector_type(4))) float  f32x4;

__device__ __forceinline__ float bf2f(unsigned short u) {
    union { unsigned int i; float f; } v;
    v.i = ((unsigned int)u) << 16;
    return v.f;
}

__device__ __forceinline__ unsigned short f2bf(float f) {
    // round-to-nearest-even truncation fp32 -> bf16
    union { float f; unsigned int i; } v;
    v.f = f;
    unsigned int x = v.i;
    unsigned int rounding = 0x7fffu + ((x >> 16) & 1u);
    x += rounding;
    return (unsigned short)(x >> 16);
}

// ---------------------------------------------------------------------------
// Kernel 1: fused Q/K projection GEMM, fp32 inputs -> bf16 outputs.
//   C[m, n] = sum_k X[m,k] * W[n,k] + bias[n]   (i.e. X @ W^T + b)
// Tile: 128x128, BK=32, 256 threads = 4 waves in 2x2, each wave 64x64 via
// 4x4 grid of 16x16x32 bf16 MFMAs. blockIdx.z selects (Wq,bq,Qb) vs (Wk,bk,Kb).
// LDS tiles padded to 40 bf16/row (80 B) to break bank-conflict strides.
// ---------------------------------------------------------------------------
__global__ __launch_bounds__(256) void proj_kernel(
    const float* __restrict__ X,
    const float* __restrict__ Wq, const float* __restrict__ bq,
    const float* __restrict__ Wk, const float* __restrict__ bk,
    unsigned short* __restrict__ Qb, unsigned short* __restrict__ Kb)
{
    __shared__ unsigned short As[128][40];
    __shared__ unsigned short Bs[128][40];

    const float* __restrict__ W    = blockIdx.z ? Wk : Wq;
    const float* __restrict__ bias = blockIdx.z ? bk : bq;
    unsigned short* __restrict__ out = blockIdx.z ? Kb : Qb;

    const int t    = threadIdx.x;
    const int M0   = blockIdx.x * 128;
    const int N0   = blockIdx.y * 128;
    const int lane = t & 63;
    const int wave = t >> 6;
    const int wm   = (wave >> 1) * 64;   // wave row offset in tile
    const int wn   = (wave & 1) * 64;    // wave col offset in tile

    const int lr = t >> 1;          // staging row this thread loads (0..127)
    const int lc = (t & 1) * 16;    // staging col offset (0 or 16)

    f32x4 acc[4][4] = {};

    for (int kt = 0; kt < EMB_DIM / 32; ++kt) {
        const int k0 = kt * 32;

        // ---- stage A tile (X rows) and B tile (W rows), fp32 -> bf16 ----
        {
            const float4* srcA = (const float4*)(X + (size_t)(M0 + lr) * EMB_DIM + k0 + lc);
            const float4* srcB = (const float4*)(W + (size_t)(N0 + lr) * EMB_DIM + k0 + lc);
            unsigned int pa[8], pb[8];
            #pragma unroll
            for (int c = 0; c < 4; ++c) {
                float4 va = srcA[c];
                float4 vb = srcB[c];
                pa[c * 2 + 0] = (unsigned int)f2bf(va.x) | ((unsigned int)f2bf(va.y) << 16);
                pa[c * 2 + 1] = (unsigned int)f2bf(va.z) | ((unsigned int)f2bf(va.w) << 16);
                pb[c * 2 + 0] = (unsigned int)f2bf(vb.x) | ((unsigned int)f2bf(vb.y) << 16);
                pb[c * 2 + 1] = (unsigned int)f2bf(vb.z) | ((unsigned int)f2bf(vb.w) << 16);
            }
            uint4* dstA = (uint4*)&As[lr][lc];
            uint4* dstB = (uint4*)&Bs[lr][lc];
            dstA[0] = make_uint4(pa[0], pa[1], pa[2], pa[3]);
            dstA[1] = make_uint4(pa[4], pa[5], pa[6], pa[7]);
            dstB[0] = make_uint4(pb[0], pb[1], pb[2], pb[3]);
            dstB[1] = make_uint4(pb[4], pb[5], pb[6], pb[7]);
        }
        __syncthreads();

        // ---- fragments: A[m=lane&15][k=(lane>>4)*8+j], B[n=lane&15][k=...] ----
        bf16x8 af[4], bff[4];
        #pragma unroll
        for (int i = 0; i < 4; ++i) {
            uint4 a = *(const uint4*)&As[wm + i * 16 + (lane & 15)][(lane >> 4) * 8];
            uint4 b = *(const uint4*)&Bs[wn + i * 16 + (lane & 15)][(lane >> 4) * 8];
            af[i]  = __builtin_bit_cast(bf16x8, a);
            bff[i] = __builtin_bit_cast(bf16x8, b);
        }
        #pragma unroll
        for (int mi = 0; mi < 4; ++mi)
            #pragma unroll
            for (int ni = 0; ni < 4; ++ni)
                acc[mi][ni] = __builtin_amdgcn_mfma_f32_16x16x32_bf16(
                    af[mi], bff[ni], acc[mi][ni], 0, 0, 0);
        __syncthreads();
    }

    // ---- epilogue: +bias, fp32 -> bf16, store. C/D: col=lane&15, row=(lane>>4)*4+r ----
    #pragma unroll
    for (int mi = 0; mi < 4; ++mi) {
        #pragma unroll
        for (int ni = 0; ni < 4; ++ni) {
            const int col = N0 + wn + ni * 16 + (lane & 15);
            const float bval = bias[col];
            #pragma unroll
            for (int r = 0; r < 4; ++r) {
                const int row = M0 + wm + mi * 16 + (lane >> 4) * 4 + r;
                out[(size_t)row * EMB_DIM + col] = f2bf(acc[mi][ni][r] + bval);
            }
        }
    }
}

// ---------------------------------------------------------------------------
// Kernel 2: one block per output row (h, n). Builds the 4096-float row in LDS
// (zeros + scattered scores), writes it out fully coalesced. Scores:
//   score[k] = dot(Q[n, h*64:...], K[idx[k], h*64:...]) / 8
// 2 threads per key (32 dims each), combined via shfl_xor. Last-write-wins
// duplicate semantics via later-occurrence scan.
// ---------------------------------------------------------------------------
__global__ __launch_bounds__(256) void scatter_kernel(
    const unsigned short* __restrict__ Qb,
    const unsigned short* __restrict__ Kb,
    const int* __restrict__ sidx,
    float* __restrict__ out)
{
    __shared__ float rowbuf[N_NODES];
    __shared__ int   sIdx[K_SPARSE];
    __shared__ float qv[HEAD_DIM];

    const int t = threadIdx.x;
    const int b = blockIdx.x;
    const int h = b >> 12;
    const int n = b & (N_NODES - 1);

    // zero the row in LDS (256 threads x 4 float4 = 4096 floats)
    float4* rowv = (float4*)rowbuf;
    float4 z4; z4.x = z4.y = z4.z = z4.w = 0.0f;
    #pragma unroll
    for (int i = 0; i < 4; ++i) rowv[t + 256 * i] = z4;

    if (t < K_SPARSE)
        sIdx[t] = sidx[((size_t)(h * N_NODES + n)) * K_SPARSE + t];
    if (t < HEAD_DIM)
        qv[t] = bf2f(Qb[(size_t)n * EMB_DIM + h * HEAD_DIM + t]);
    __syncthreads();

    const int k    = t >> 1;
    const int half = t & 1;
    const int myidx = sIdx[k];

    // gather 32 bf16 (64 B) of this key's head-slice: 4 x uint4 loads
    const uint4* krow = (const uint4*)(Kb + (size_t)myidx * EMB_DIM + h * HEAD_DIM + half * 32);
    float acc = 0.0f;
    #pragma unroll
    for (int c = 0; c < 4; ++c) {
        uint4 u = krow[c];
        unsigned int uu[4] = {u.x, u.y, u.z, u.w};
        #pragma unroll
        for (int j = 0; j < 4; ++j) {
            float lo = bf2f((unsigned short)(uu[j] & 0xffffu));
            float hi = bf2f((unsigned short)(uu[j] >> 16));
            acc += lo * qv[half * 32 + c * 8 + j * 2 + 0];
            acc += hi * qv[half * 32 + c * 8 + j * 2 + 1];
        }
    }
    acc += __shfl_xor(acc, 1);

    if (half == 0) {
        const float score = acc * 0.125f;  // 1/sqrt(64)
        // last-write-wins: only scatter if no later key has the same index
        bool win = true;
        for (int k2 = k + 1; k2 < K_SPARSE; ++k2) {
            if (sIdx[k2] == myidx) { win = false; break; }
        }
        if (win) rowbuf[myidx] = score;
    }
    __syncthreads();

    // coalesced row write: 16 KB
    float4* orowv = (float4*)(out + ((size_t)(h * N_NODES + n)) * N_NODES);
    #pragma unroll
    for (int i = 0; i < 4; ++i) orowv[t + 256 * i] = rowv[t + 256 * i];
}

extern "C" void kernel_launch(void* const* d_in, const int* in_sizes, int n_in,
                              void* d_out, int out_size, void* d_ws, size_t ws_size,
                              hipStream_t stream) {
    const float* emb = (const float*)d_in[0];
    const float* Wq  = (const float*)d_in[1];
    const float* bq  = (const float*)d_in[2];
    const float* Wk  = (const float*)d_in[3];
    const float* bk  = (const float*)d_in[4];
    const int*   si  = (const int*)d_in[5];
    float* out = (float*)d_out;

    // workspace: Qb (4 MB) + Kb (4 MB) bf16
    unsigned short* Qb = (unsigned short*)d_ws;
    unsigned short* Kb = Qb + (size_t)N_NODES * EMB_DIM;

    dim3 pg(N_NODES / 128, EMB_DIM / 128, 2);   // 32 x 4 x 2 = 256 blocks
    proj_kernel<<<pg, 256, 0, stream>>>(emb, Wq, bq, Wk, bk, Qb, Kb);

    scatter_kernel<<<N_HEADS * N_NODES, 256, 0, stream>>>(Qb, Kb, si, out);
}

// Round 2
// 614.716 us; speedup vs baseline: 1.2334x; 1.2334x over previous
//
#include <hip/hip_runtime.h>
#include <hip/hip_bf16.h>
#include <stdint.h>

// Problem constants (from reference)
#define N_NODES  4096
#define EMB_DIM  512
#define N_HEADS  8
#define K_SPARSE 128
#define HEAD_DIM 64   // EMB_DIM / N_HEADS

typedef __attribute__((ext_vector_type(8))) __bf16 bf16x8;
typedef __attribute__((ext_vector_type(4))) float  f32x4;

__device__ __forceinline__ float bf2f(unsigned short u) {
    union { unsigned int i; float f; } v;
    v.i = ((unsigned int)u) << 16;
    return v.f;
}

__device__ __forceinline__ unsigned short f2bf(float f) {
    // round-to-nearest-even fp32 -> bf16
    union { float f; unsigned int i; } v;
    v.f = f;
    unsigned int x = v.i;
    unsigned int rounding = 0x7fffu + ((x >> 16) & 1u);
    x += rounding;
    return (unsigned short)(x >> 16);
}

// ---------------------------------------------------------------------------
// Kernel 1: fused Q/K projection GEMM, fp32 inputs -> bf16 outputs.
//   C[m, n] = sum_k X[m,k] * W[n,k] + bias[n]   (X @ W^T + b)
// Tile: 128x128, BK=32, 256 threads = 4 waves (2x2), each wave 64x64 via
// 4x4 grid of 16x16x32 bf16 MFMAs. blockIdx.z selects (Wq,bq,Qb) vs (Wk,bk,Kb).
// ---------------------------------------------------------------------------
__global__ __launch_bounds__(256) void proj_kernel(
    const float* __restrict__ X,
    const float* __restrict__ Wq, const float* __restrict__ bq,
    const float* __restrict__ Wk, const float* __restrict__ bk,
    unsigned short* __restrict__ Qb, unsigned short* __restrict__ Kb)
{
    __shared__ unsigned short As[128][40];
    __shared__ unsigned short Bs[128][40];

    const float* __restrict__ W    = blockIdx.z ? Wk : Wq;
    const float* __restrict__ bias = blockIdx.z ? bk : bq;
    unsigned short* __restrict__ out = blockIdx.z ? Kb : Qb;

    const int t    = threadIdx.x;
    const int M0   = blockIdx.x * 128;
    const int N0   = blockIdx.y * 128;
    const int lane = t & 63;
    const int wave = t >> 6;
    const int wm   = (wave >> 1) * 64;
    const int wn   = (wave & 1) * 64;

    const int lr = t >> 1;          // staging row (0..127)
    const int lc = (t & 1) * 16;    // staging col offset (0 or 16)

    f32x4 acc[4][4] = {};

    for (int kt = 0; kt < EMB_DIM / 32; ++kt) {
        const int k0 = kt * 32;
        {
            const float4* srcA = (const float4*)(X + (size_t)(M0 + lr) * EMB_DIM + k0 + lc);
            const float4* srcB = (const float4*)(W + (size_t)(N0 + lr) * EMB_DIM + k0 + lc);
            unsigned int pa[8], pb[8];
            #pragma unroll
            for (int c = 0; c < 4; ++c) {
                float4 va = srcA[c];
                float4 vb = srcB[c];
                pa[c * 2 + 0] = (unsigned int)f2bf(va.x) | ((unsigned int)f2bf(va.y) << 16);
                pa[c * 2 + 1] = (unsigned int)f2bf(va.z) | ((unsigned int)f2bf(va.w) << 16);
                pb[c * 2 + 0] = (unsigned int)f2bf(vb.x) | ((unsigned int)f2bf(vb.y) << 16);
                pb[c * 2 + 1] = (unsigned int)f2bf(vb.z) | ((unsigned int)f2bf(vb.w) << 16);
            }
            uint4* dstA = (uint4*)&As[lr][lc];
            uint4* dstB = (uint4*)&Bs[lr][lc];
            dstA[0] = make_uint4(pa[0], pa[1], pa[2], pa[3]);
            dstA[1] = make_uint4(pa[4], pa[5], pa[6], pa[7]);
            dstB[0] = make_uint4(pb[0], pb[1], pb[2], pb[3]);
            dstB[1] = make_uint4(pb[4], pb[5], pb[6], pb[7]);
        }
        __syncthreads();

        bf16x8 af[4], bff[4];
        #pragma unroll
        for (int i = 0; i < 4; ++i) {
            uint4 a = *(const uint4*)&As[wm + i * 16 + (lane & 15)][(lane >> 4) * 8];
            uint4 b = *(const uint4*)&Bs[wn + i * 16 + (lane & 15)][(lane >> 4) * 8];
            af[i]  = __builtin_bit_cast(bf16x8, a);
            bff[i] = __builtin_bit_cast(bf16x8, b);
        }
        #pragma unroll
        for (int mi = 0; mi < 4; ++mi)
            #pragma unroll
            for (int ni = 0; ni < 4; ++ni)
                acc[mi][ni] = __builtin_amdgcn_mfma_f32_16x16x32_bf16(
                    af[mi], bff[ni], acc[mi][ni], 0, 0, 0);
        __syncthreads();
    }

    // epilogue: +bias, fp32 -> bf16. C/D map: col=lane&15, row=(lane>>4)*4+r
    #pragma unroll
    for (int mi = 0; mi < 4; ++mi) {
        #pragma unroll
        for (int ni = 0; ni < 4; ++ni) {
            const int col = N0 + wn + ni * 16 + (lane & 15);
            const float bval = bias[col];
            #pragma unroll
            for (int r = 0; r < 4; ++r) {
                const int row = M0 + wm + mi * 16 + (lane >> 4) * 4 + r;
                out[(size_t)row * EMB_DIM + col] = f2bf(acc[mi][ni][r] + bval);
            }
        }
    }
}

// ---------------------------------------------------------------------------
// Kernel 2: one block per output row (h, n). Builds the 4096-float row in LDS
// (zeros + scattered scores), writes it out coalesced.
// Duplicate-index semantics (last write wins) via O(K) LDS atomicMax ticket:
//   phase 1: rowbuf zeroed (bit pattern 0 == 0.0f)
//   phase 2: each key k does atomicMax((uint*)&rowbuf[idx], k+1)
//   phase 3: key k "wins" iff tag == k+1 (largest k at idx = last occurrence)
//   phase 4: winners overwrite the tag with the float score
// Untouched slots keep bit-zero = 0.0f. No O(K^2) latency-chained scan.
// ---------------------------------------------------------------------------
__global__ __launch_bounds__(256) void scatter_kernel(
    const unsigned short* __restrict__ Qb,
    const unsigned short* __restrict__ Kb,
    const int* __restrict__ sidx,
    float* __restrict__ out)
{
    __shared__ float rowbuf[N_NODES];
    __shared__ int   sIdx[K_SPARSE];
    __shared__ float qv[HEAD_DIM];

    const int t = threadIdx.x;
    const int b = blockIdx.x;
    const int h = b >> 12;
    const int n = b & (N_NODES - 1);

    // zero the row in LDS (256 threads x 4 float4 = 4096 floats)
    float4* rowv = (float4*)rowbuf;
    float4 z4; z4.x = z4.y = z4.z = z4.w = 0.0f;
    #pragma unroll
    for (int i = 0; i < 4; ++i) rowv[t + 256 * i] = z4;

    if (t < K_SPARSE)
        sIdx[t] = sidx[((size_t)(h * N_NODES + n)) * K_SPARSE + t];
    if (t < HEAD_DIM)
        qv[t] = bf2f(Qb[(size_t)n * EMB_DIM + h * HEAD_DIM + t]);
    __syncthreads();

    const int k     = t >> 1;
    const int half  = t & 1;
    const int myidx = sIdx[k];

    // ticket race (independent of the gather below; only needs sIdx)
    unsigned int* tags = (unsigned int*)rowbuf;
    if (half == 0) atomicMax(&tags[myidx], (unsigned int)(k + 1));

    // gather 32 bf16 (64 B) of this key's head-slice: 4 x uint4 loads
    const uint4* krow = (const uint4*)(Kb + (size_t)myidx * EMB_DIM + h * HEAD_DIM + half * 32);
    float acc = 0.0f;
    #pragma unroll
    for (int c = 0; c < 4; ++c) {
        uint4 u = krow[c];
        unsigned int uu[4] = {u.x, u.y, u.z, u.w};
        #pragma unroll
        for (int j = 0; j < 4; ++j) {
            float lo = bf2f((unsigned short)(uu[j] & 0xffffu));
            float hi = bf2f((unsigned short)(uu[j] >> 16));
            acc += lo * qv[half * 32 + c * 8 + j * 2 + 0];
            acc += hi * qv[half * 32 + c * 8 + j * 2 + 1];
        }
    }
    acc += __shfl_xor(acc, 1);

    __syncthreads();   // all atomicMax tickets visible

    const bool win = (half == 0) && (tags[myidx] == (unsigned int)(k + 1));
    const float score = acc * 0.125f;  // 1/sqrt(64)

    __syncthreads();   // all tag reads done before float overwrite

    if (win) rowbuf[myidx] = score;

    __syncthreads();

    // coalesced row write: 16 KB
    float4* orowv = (float4*)(out + ((size_t)(h * N_NODES + n)) * N_NODES);
    #pragma unroll
    for (int i = 0; i < 4; ++i) orowv[t + 256 * i] = rowv[t + 256 * i];
}

extern "C" void kernel_launch(void* const* d_in, const int* in_sizes, int n_in,
                              void* d_out, int out_size, void* d_ws, size_t ws_size,
                              hipStream_t stream) {
    const float* emb = (const float*)d_in[0];
    const float* Wq  = (const float*)d_in[1];
    const float* bq  = (const float*)d_in[2];
    const float* Wk  = (const float*)d_in[3];
    const float* bk  = (const float*)d_in[4];
    const int*   si  = (const int*)d_in[5];
    float* out = (float*)d_out;

    // workspace: Qb (4 MB) + Kb (4 MB) bf16
    unsigned short* Qb = (unsigned short*)d_ws;
    unsigned short* Kb = Qb + (size_t)N_NODES * EMB_DIM;

    dim3 pg(N_NODES / 128, EMB_DIM / 128, 2);   // 32 x 4 x 2 = 256 blocks
    proj_kernel<<<pg, 256, 0, stream>>>(emb, Wq, bq, Wk, bk, Qb, Kb);

    scatter_kernel<<<N_HEADS * N_NODES, 256, 0, stream>>>(Qb, Kb, si, out);
}

// Round 4
// 582.002 us; speedup vs baseline: 1.3028x; 1.0562x over previous
//
#include <hip/hip_runtime.h>
#include <hip/hip_bf16.h>
#include <stdint.h>

// Problem constants (from reference)
#define N_NODES  4096
#define EMB_DIM  512
#define N_HEADS  8
#define K_SPARSE 128
#define HEAD_DIM 64   // EMB_DIM / N_HEADS

typedef __attribute__((ext_vector_type(8))) __bf16 bf16x8;
typedef __attribute__((ext_vector_type(4))) float  f32x4;

__device__ __forceinline__ float bf2f(unsigned short u) {
    union { unsigned int i; float f; } v;
    v.i = ((unsigned int)u) << 16;
    return v.f;
}

__device__ __forceinline__ unsigned short f2bf(float f) {
    // round-to-nearest-even fp32 -> bf16
    union { float f; unsigned int i; } v;
    v.f = f;
    unsigned int x = v.i;
    unsigned int rounding = 0x7fffu + ((x >> 16) & 1u);
    x += rounding;
    return (unsigned short)(x >> 16);
}

// ---------------------------------------------------------------------------
// Kernel 1: fused Q/K projection GEMM, fp32 inputs -> bf16 outputs.
//   C[m, n] = sum_k X[m,k] * W[n,k] + bias[n]   (X @ W^T + b)
// Tile: 64x128, BK=32, 256 threads = 4 waves (2x2), each wave 32x64 via
// 2x4 grid of 16x16x32 bf16 MFMAs. Grid = 64 x 4 x 2 = 512 blocks
// (2 blocks/CU so barriers of one block overlap compute of the other).
// blockIdx.z selects (Wq,bq,Qb) vs (Wk,bk,Kb).
// ---------------------------------------------------------------------------
__global__ __launch_bounds__(256) void proj_kernel(
    const float* __restrict__ X,
    const float* __restrict__ Wq, const float* __restrict__ bq,
    const float* __restrict__ Wk, const float* __restrict__ bk,
    unsigned short* __restrict__ Qb, unsigned short* __restrict__ Kb)
{
    __shared__ unsigned short As[64][40];    // 64 rows x 32 bf16 (+pad)
    __shared__ unsigned short Bs[128][40];   // 128 rows x 32 bf16 (+pad)

    const float* __restrict__ W    = blockIdx.z ? Wk : Wq;
    const float* __restrict__ bias = blockIdx.z ? bk : bq;
    unsigned short* __restrict__ out = blockIdx.z ? Kb : Qb;

    const int t    = threadIdx.x;
    const int M0   = blockIdx.x * 64;
    const int N0   = blockIdx.y * 128;
    const int lane = t & 63;
    const int wave = t >> 6;
    const int wm   = (wave >> 1) * 32;   // wave row offset (0 or 32)
    const int wn   = (wave & 1) * 64;    // wave col offset (0 or 64)

    // A staging: 64 rows x 32 fp32; thread -> row t>>2, col (t&3)*8 (8 floats)
    const int arow = t >> 2;
    const int acol = (t & 3) * 8;
    // B staging: 128 rows x 32 fp32; thread -> row t>>1, col (t&1)*16 (16 floats)
    const int brow = t >> 1;
    const int bcol = (t & 1) * 16;

    f32x4 acc[2][4] = {};

    for (int kt = 0; kt < EMB_DIM / 32; ++kt) {
        const int k0 = kt * 32;
        {
            const float4* srcA = (const float4*)(X + (size_t)(M0 + arow) * EMB_DIM + k0 + acol);
            float4 va0 = srcA[0], va1 = srcA[1];
            unsigned int pa[4];
            pa[0] = (unsigned int)f2bf(va0.x) | ((unsigned int)f2bf(va0.y) << 16);
            pa[1] = (unsigned int)f2bf(va0.z) | ((unsigned int)f2bf(va0.w) << 16);
            pa[2] = (unsigned int)f2bf(va1.x) | ((unsigned int)f2bf(va1.y) << 16);
            pa[3] = (unsigned int)f2bf(va1.z) | ((unsigned int)f2bf(va1.w) << 16);
            *(uint4*)&As[arow][acol] = make_uint4(pa[0], pa[1], pa[2], pa[3]);

            const float4* srcB = (const float4*)(W + (size_t)(N0 + brow) * EMB_DIM + k0 + bcol);
            unsigned int pb[8];
            #pragma unroll
            for (int c = 0; c < 4; ++c) {
                float4 vb = srcB[c];
                pb[c * 2 + 0] = (unsigned int)f2bf(vb.x) | ((unsigned int)f2bf(vb.y) << 16);
                pb[c * 2 + 1] = (unsigned int)f2bf(vb.z) | ((unsigned int)f2bf(vb.w) << 16);
            }
            uint4* dstB = (uint4*)&Bs[brow][bcol];
            dstB[0] = make_uint4(pb[0], pb[1], pb[2], pb[3]);
            dstB[1] = make_uint4(pb[4], pb[5], pb[6], pb[7]);
        }
        __syncthreads();

        // fragments: A[m=lane&15][k=(lane>>4)*8+j], B[n=lane&15][k=...]
        bf16x8 af[2], bff[4];
        #pragma unroll
        for (int i = 0; i < 2; ++i)
            af[i] = __builtin_bit_cast(bf16x8,
                *(const uint4*)&As[wm + i * 16 + (lane & 15)][(lane >> 4) * 8]);
        #pragma unroll
        for (int i = 0; i < 4; ++i)
            bff[i] = __builtin_bit_cast(bf16x8,
                *(const uint4*)&Bs[wn + i * 16 + (lane & 15)][(lane >> 4) * 8]);

        #pragma unroll
        for (int mi = 0; mi < 2; ++mi)
            #pragma unroll
            for (int ni = 0; ni < 4; ++ni)
                acc[mi][ni] = __builtin_amdgcn_mfma_f32_16x16x32_bf16(
                    af[mi], bff[ni], acc[mi][ni], 0, 0, 0);
        __syncthreads();
    }

    // epilogue: +bias, fp32 -> bf16. C/D map: col=lane&15, row=(lane>>4)*4+r
    #pragma unroll
    for (int mi = 0; mi < 2; ++mi) {
        #pragma unroll
        for (int ni = 0; ni < 4; ++ni) {
            const int col = N0 + wn + ni * 16 + (lane & 15);
            const float bval = bias[col];
            #pragma unroll
            for (int r = 0; r < 4; ++r) {
                const int row = M0 + wm + mi * 16 + (lane >> 4) * 4 + r;
                out[(size_t)row * EMB_DIM + col] = f2bf(acc[mi][ni][r] + bval);
            }
        }
    }
}

// ---------------------------------------------------------------------------
// Kernel 2: one block per output row (h, n). Builds the 4096-float row in LDS
// (zeros + scattered scores), writes it out coalesced with NONTEMPORAL stores
// (output is write-once never-read; nt keeps the 4 MB K-table L2-resident
// instead of being thrashed by the 537 MB write stream).
// Duplicate-index semantics (last write wins) via O(K) LDS atomicMax ticket.
// ---------------------------------------------------------------------------
__global__ __launch_bounds__(256) void scatter_kernel(
    const unsigned short* __restrict__ Qb,
    const unsigned short* __restrict__ Kb,
    const int* __restrict__ sidx,
    float* __restrict__ out)
{
    __shared__ float rowbuf[N_NODES];
    __shared__ int   sIdx[K_SPARSE];
    __shared__ float qv[HEAD_DIM];

    const int t = threadIdx.x;
    const int b = blockIdx.x;
    const int h = b >> 12;
    const int n = b & (N_NODES - 1);

    // issue global loads FIRST so they overlap the LDS zero-fill
    int   myIdxLd = 0;
    float myQLd   = 0.0f;
    if (t < K_SPARSE)
        myIdxLd = sidx[((size_t)(h * N_NODES + n)) * K_SPARSE + t];
    if (t < HEAD_DIM)
        myQLd = bf2f(Qb[(size_t)n * EMB_DIM + h * HEAD_DIM + t]);

    // zero the row in LDS (256 threads x 4 f32x4 = 4096 floats)
    f32x4* rowv = (f32x4*)rowbuf;
    const f32x4 z4 = {0.0f, 0.0f, 0.0f, 0.0f};
    #pragma unroll
    for (int i = 0; i < 4; ++i) rowv[t + 256 * i] = z4;

    if (t < K_SPARSE) sIdx[t] = myIdxLd;
    if (t < HEAD_DIM) qv[t]   = myQLd;
    __syncthreads();

    const int k     = t >> 1;
    const int half  = t & 1;
    const int myidx = sIdx[k];

    // ticket race (only needs sIdx + zeroed rowbuf)
    unsigned int* tags = (unsigned int*)rowbuf;
    if (half == 0) atomicMax(&tags[myidx], (unsigned int)(k + 1));

    // gather 32 bf16 (64 B) of this key's head-slice: 4 x uint4 loads
    const uint4* krow = (const uint4*)(Kb + (size_t)myidx * EMB_DIM + h * HEAD_DIM + half * 32);
    float acc = 0.0f;
    #pragma unroll
    for (int c = 0; c < 4; ++c) {
        uint4 u = krow[c];
        unsigned int uu[4] = {u.x, u.y, u.z, u.w};
        #pragma unroll
        for (int j = 0; j < 4; ++j) {
            float lo = bf2f((unsigned short)(uu[j] & 0xffffu));
            float hi = bf2f((unsigned short)(uu[j] >> 16));
            acc += lo * qv[half * 32 + c * 8 + j * 2 + 0];
            acc += hi * qv[half * 32 + c * 8 + j * 2 + 1];
        }
    }
    acc += __shfl_xor(acc, 1);

    __syncthreads();   // all atomicMax tickets visible

    const bool win = (half == 0) && (tags[myidx] == (unsigned int)(k + 1));
    const float score = acc * 0.125f;  // 1/sqrt(64)

    __syncthreads();   // all tag reads done before float overwrite

    if (win) rowbuf[myidx] = score;

    __syncthreads();

    // coalesced nontemporal row write: 16 KB
    f32x4* orowv = (f32x4*)(out + ((size_t)(h * N_NODES + n)) * N_NODES);
    #pragma unroll
    for (int i = 0; i < 4; ++i)
        __builtin_nontemporal_store(rowv[t + 256 * i], &orowv[t + 256 * i]);
}

extern "C" void kernel_launch(void* const* d_in, const int* in_sizes, int n_in,
                              void* d_out, int out_size, void* d_ws, size_t ws_size,
                              hipStream_t stream) {
    const float* emb = (const float*)d_in[0];
    const float* Wq  = (const float*)d_in[1];
    const float* bq  = (const float*)d_in[2];
    const float* Wk  = (const float*)d_in[3];
    const float* bk  = (const float*)d_in[4];
    const int*   si  = (const int*)d_in[5];
    float* out = (float*)d_out;

    // workspace: Qb (4 MB) + Kb (4 MB) bf16
    unsigned short* Qb = (unsigned short*)d_ws;
    unsigned short* Kb = Qb + (size_t)N_NODES * EMB_DIM;

    dim3 pg(N_NODES / 64, EMB_DIM / 128, 2);   // 64 x 4 x 2 = 512 blocks
    proj_kernel<<<pg, 256, 0, stream>>>(emb, Wq, bq, Wk, bk, Qb, Kb);

    scatter_kernel<<<N_HEADS * N_NODES, 256, 0, stream>>>(Qb, Kb, si, out);
}

// Round 5
// 559.438 us; speedup vs baseline: 1.3553x; 1.0403x over previous
//
#include <hip/hip_runtime.h>
#include <hip/hip_bf16.h>
#include <stdint.h>

// Problem constants (from reference)
#define N_NODES  4096
#define EMB_DIM  512
#define N_HEADS  8
#define K_SPARSE 128
#define HEAD_DIM 64   // EMB_DIM / N_HEADS

typedef __attribute__((ext_vector_type(8))) __bf16 bf16x8;
typedef __attribute__((ext_vector_type(4))) float  f32x4;

__device__ __forceinline__ float bf2f(unsigned short u) {
    union { unsigned int i; float f; } v;
    v.i = ((unsigned int)u) << 16;
    return v.f;
}

__device__ __forceinline__ unsigned short f2bf(float f) {
    // round-to-nearest-even fp32 -> bf16
    union { float f; unsigned int i; } v;
    v.f = f;
    unsigned int x = v.i;
    unsigned int rounding = 0x7fffu + ((x >> 16) & 1u);
    x += rounding;
    return (unsigned short)(x >> 16);
}

// ---------------------------------------------------------------------------
// Kernel 1: fused Q/K projection GEMM, fp32 inputs -> bf16 outputs.
//   C[m, n] = sum_k X[m,k] * W[n,k] + bias[n]   (X @ W^T + b)
// Tile: 64x128, BK=32, 256 threads = 4 waves (2x2), each wave 32x64 via
// 2x4 grid of 16x16x32 bf16 MFMAs. Grid = 64 x 4 x 2 = 512 blocks.
// ---------------------------------------------------------------------------
__global__ __launch_bounds__(256) void proj_kernel(
    const float* __restrict__ X,
    const float* __restrict__ Wq, const float* __restrict__ bq,
    const float* __restrict__ Wk, const float* __restrict__ bk,
    unsigned short* __restrict__ Qb, unsigned short* __restrict__ Kb)
{
    __shared__ unsigned short As[64][40];    // 64 rows x 32 bf16 (+pad)
    __shared__ unsigned short Bs[128][40];   // 128 rows x 32 bf16 (+pad)

    const float* __restrict__ W    = blockIdx.z ? Wk : Wq;
    const float* __restrict__ bias = blockIdx.z ? bk : bq;
    unsigned short* __restrict__ out = blockIdx.z ? Kb : Qb;

    const int t    = threadIdx.x;
    const int M0   = blockIdx.x * 64;
    const int N0   = blockIdx.y * 128;
    const int lane = t & 63;
    const int wave = t >> 6;
    const int wm   = (wave >> 1) * 32;   // wave row offset (0 or 32)
    const int wn   = (wave & 1) * 64;    // wave col offset (0 or 64)

    const int arow = t >> 2;
    const int acol = (t & 3) * 8;
    const int brow = t >> 1;
    const int bcol = (t & 1) * 16;

    f32x4 acc[2][4] = {};

    for (int kt = 0; kt < EMB_DIM / 32; ++kt) {
        const int k0 = kt * 32;
        {
            const float4* srcA = (const float4*)(X + (size_t)(M0 + arow) * EMB_DIM + k0 + acol);
            float4 va0 = srcA[0], va1 = srcA[1];
            unsigned int pa[4];
            pa[0] = (unsigned int)f2bf(va0.x) | ((unsigned int)f2bf(va0.y) << 16);
            pa[1] = (unsigned int)f2bf(va0.z) | ((unsigned int)f2bf(va0.w) << 16);
            pa[2] = (unsigned int)f2bf(va1.x) | ((unsigned int)f2bf(va1.y) << 16);
            pa[3] = (unsigned int)f2bf(va1.z) | ((unsigned int)f2bf(va1.w) << 16);
            *(uint4*)&As[arow][acol] = make_uint4(pa[0], pa[1], pa[2], pa[3]);

            const float4* srcB = (const float4*)(W + (size_t)(N0 + brow) * EMB_DIM + k0 + bcol);
            unsigned int pb[8];
            #pragma unroll
            for (int c = 0; c < 4; ++c) {
                float4 vb = srcB[c];
                pb[c * 2 + 0] = (unsigned int)f2bf(vb.x) | ((unsigned int)f2bf(vb.y) << 16);
                pb[c * 2 + 1] = (unsigned int)f2bf(vb.z) | ((unsigned int)f2bf(vb.w) << 16);
            }
            uint4* dstB = (uint4*)&Bs[brow][bcol];
            dstB[0] = make_uint4(pb[0], pb[1], pb[2], pb[3]);
            dstB[1] = make_uint4(pb[4], pb[5], pb[6], pb[7]);
        }
        __syncthreads();

        bf16x8 af[2], bff[4];
        #pragma unroll
        for (int i = 0; i < 2; ++i)
            af[i] = __builtin_bit_cast(bf16x8,
                *(const uint4*)&As[wm + i * 16 + (lane & 15)][(lane >> 4) * 8]);
        #pragma unroll
        for (int i = 0; i < 4; ++i)
            bff[i] = __builtin_bit_cast(bf16x8,
                *(const uint4*)&Bs[wn + i * 16 + (lane & 15)][(lane >> 4) * 8]);

        #pragma unroll
        for (int mi = 0; mi < 2; ++mi)
            #pragma unroll
            for (int ni = 0; ni < 4; ++ni)
                acc[mi][ni] = __builtin_amdgcn_mfma_f32_16x16x32_bf16(
                    af[mi], bff[ni], acc[mi][ni], 0, 0, 0);
        __syncthreads();
    }

    // epilogue: +bias, fp32 -> bf16. C/D map: col=lane&15, row=(lane>>4)*4+r
    #pragma unroll
    for (int mi = 0; mi < 2; ++mi) {
        #pragma unroll
        for (int ni = 0; ni < 4; ++ni) {
            const int col = N0 + wn + ni * 16 + (lane & 15);
            const float bval = bias[col];
            #pragma unroll
            for (int r = 0; r < 4; ++r) {
                const int row = M0 + wm + mi * 16 + (lane >> 4) * 4 + r;
                out[(size_t)row * EMB_DIM + col] = f2bf(acc[mi][ni][r] + bval);
            }
        }
    }
}

// ---------------------------------------------------------------------------
// Kernel 2: one block per output row (h, n).
// Sectored gather: 8 lanes per key, lane j loads bytes [16j,16j+16) of the
// key's 128 B head-slice -> one wave-instruction covers 8 keys / 16 cache
// lines, each line fully consumed by 4 contiguous lanes (vs 64 partial lines
// with the old 2-thread/key layout). 4 iterations cover all 128 keys; 8-lane
// shfl_xor reduction forms the dot product.
// Duplicate-index semantics (last write wins) via O(K) LDS atomicMax ticket.
// Output row written with nontemporal stores (write-once, never re-read).
// ---------------------------------------------------------------------------
__global__ __launch_bounds__(256) void scatter_kernel(
    const unsigned short* __restrict__ Qb,
    const unsigned short* __restrict__ Kb,
    const int* __restrict__ sidx,
    float* __restrict__ out)
{
    __shared__ float rowbuf[N_NODES];
    __shared__ int   sIdx[K_SPARSE];

    const int t = threadIdx.x;
    const int b = blockIdx.x;
    const int h = b >> 12;
    const int n = b & (N_NODES - 1);
    const int j = t & 7;            // sector lane within key group

    // issue independent global loads first
    // Q slice: 8 bf16 (16 B) this lane needs, broadcast across each 8-lane group
    const uint4 qu = *(const uint4*)(Qb + (size_t)n * EMB_DIM + h * HEAD_DIM + j * 8);
    int myIdxLd = 0;
    if (t < K_SPARSE)
        myIdxLd = sidx[((size_t)(h * N_NODES + n)) * K_SPARSE + t];

    // zero the row in LDS (256 threads x 4 f32x4 = 4096 floats)
    f32x4* rowv = (f32x4*)rowbuf;
    const f32x4 z4 = {0.0f, 0.0f, 0.0f, 0.0f};
    #pragma unroll
    for (int i = 0; i < 4; ++i) rowv[t + 256 * i] = z4;

    if (t < K_SPARSE) sIdx[t] = myIdxLd;

    // unpack this lane's 8 Q values
    float q[8];
    {
        unsigned int uu[4] = {qu.x, qu.y, qu.z, qu.w};
        #pragma unroll
        for (int w = 0; w < 4; ++w) {
            q[2 * w + 0] = bf2f((unsigned short)(uu[w] & 0xffffu));
            q[2 * w + 1] = bf2f((unsigned short)(uu[w] >> 16));
        }
    }
    __syncthreads();

    // ticket race: one thread per key (uses register idx, no LDS re-read)
    unsigned int* tags = (unsigned int*)rowbuf;
    if (t < K_SPARSE) atomicMax(&tags[myIdxLd], (unsigned int)(t + 1));

    // sectored gather + dot: key kk = (t>>3) + 32*iter, lane j covers 8 dims
    float score[4];
    int   kidx[4];
    #pragma unroll
    for (int iter = 0; iter < 4; ++iter) {
        const int kk  = (t >> 3) + 32 * iter;
        const int idx = sIdx[kk];
        kidx[iter] = idx;
        const uint4 u = *(const uint4*)(Kb + (size_t)idx * EMB_DIM + h * HEAD_DIM + j * 8);
        unsigned int uu[4] = {u.x, u.y, u.z, u.w};
        float acc = 0.0f;
        #pragma unroll
        for (int w = 0; w < 4; ++w) {
            acc += bf2f((unsigned short)(uu[w] & 0xffffu)) * q[2 * w + 0];
            acc += bf2f((unsigned short)(uu[w] >> 16))     * q[2 * w + 1];
        }
        // reduce across the 8-lane group
        acc += __shfl_xor(acc, 1);
        acc += __shfl_xor(acc, 2);
        acc += __shfl_xor(acc, 4);
        score[iter] = acc * 0.125f;   // 1/sqrt(64)
    }

    __syncthreads();   // all atomicMax tickets visible

    bool win[4];
    #pragma unroll
    for (int iter = 0; iter < 4; ++iter) {
        const int kk = (t >> 3) + 32 * iter;
        win[iter] = (j == 0) && (tags[kidx[iter]] == (unsigned int)(kk + 1));
    }

    __syncthreads();   // all tag reads done before float overwrite

    #pragma unroll
    for (int iter = 0; iter < 4; ++iter)
        if (win[iter]) rowbuf[kidx[iter]] = score[iter];

    __syncthreads();

    // coalesced nontemporal row write: 16 KB
    f32x4* orowv = (f32x4*)(out + ((size_t)(h * N_NODES + n)) * N_NODES);
    #pragma unroll
    for (int i = 0; i < 4; ++i)
        __builtin_nontemporal_store(rowv[t + 256 * i], &orowv[t + 256 * i]);
}

extern "C" void kernel_launch(void* const* d_in, const int* in_sizes, int n_in,
                              void* d_out, int out_size, void* d_ws, size_t ws_size,
                              hipStream_t stream) {
    const float* emb = (const float*)d_in[0];
    const float* Wq  = (const float*)d_in[1];
    const float* bq  = (const float*)d_in[2];
    const float* Wk  = (const float*)d_in[3];
    const float* bk  = (const float*)d_in[4];
    const int*   si  = (const int*)d_in[5];
    float* out = (float*)d_out;

    // workspace: Qb (4 MB) + Kb (4 MB) bf16
    unsigned short* Qb = (unsigned short*)d_ws;
    unsigned short* Kb = Qb + (size_t)N_NODES * EMB_DIM;

    dim3 pg(N_NODES / 64, EMB_DIM / 128, 2);   // 64 x 4 x 2 = 512 blocks
    proj_kernel<<<pg, 256, 0, stream>>>(emb, Wq, bq, Wk, bk, Qb, Kb);

    scatter_kernel<<<N_HEADS * N_NODES, 256, 0, stream>>>(Qb, Kb, si, out);
}